// Round 2
// baseline (792.836 us; speedup 1.0000x reference)
//
#include <hip/hip_runtime.h>
#include <hip/hip_bf16.h>

#define Bb 2
#define HD 96
#define DI 192
#define LL 4096
#define Kd 4
#define Ns 16
#define Rr 6
#define DBLd 38
#define SEG 64
#define SEGLEN 64
#define NBKCN (Bb*Kd*DI*Ns)   // 24576
#define LNEPS 1e-5f

// generic 1x1 conv: out[b,o,l] = sum_i w[o,i] * x[b,i,l]
// grid: (LL/256, Cout/4, Bb); weights uniform per block -> s_loads
__global__ __launch_bounds__(256) void k_conv1x1(const float* __restrict__ x,
    const float* __restrict__ w, float* __restrict__ out, int Cin, int Cout) {
  int l = blockIdx.x*256 + threadIdx.x;
  int o0 = blockIdx.y*4;
  int b = blockIdx.z;
  const float* xb = x + ((size_t)b*Cin)*LL + l;
  const float* w0 = w + (size_t)o0*Cin;
  float a0=0.f,a1=0.f,a2=0.f,a3=0.f;
  for (int i=0;i<Cin;i++) {
    float xv = xb[(size_t)i*LL];
    a0 += w0[i]*xv;
    a1 += w0[Cin+i]*xv;
    a2 += w0[2*Cin+i]*xv;
    a3 += w0[3*Cin+i]*xv;
  }
  float* ob = out + ((size_t)b*Cout + o0)*LL + l;
  ob[0]=a0; ob[LL]=a1; ob[2*(size_t)LL]=a2; ob[3*(size_t)LL]=a3;
}

// channel LayerNorm in-place over C at each (b,l)
__global__ __launch_bounds__(256) void k_chanln(float* __restrict__ t,
    const float* __restrict__ g, const float* __restrict__ be, int C) {
  int tt = blockIdx.x*256 + threadIdx.x; // b*LL + l
  int l = tt & (LL-1); int b = tt >> 12;
  float* col = t + (size_t)b*C*LL + l;
  float s=0.f, s2=0.f;
  for (int i=0;i<C;i++) { float v = col[(size_t)i*LL]; s+=v; s2+=v*v; }
  float mu = s/(float)C;
  float var = s2/(float)C - mu*mu;
  float r = rsqrtf(var + LNEPS);
  for (int i=0;i<C;i++) {
    float v = col[(size_t)i*LL];
    col[(size_t)i*LL] = (v-mu)*r*g[i] + be[i];
  }
}

// depthwise 3x3 SAME + bias + silu, then scatter into the 4 direction copies
__global__ __launch_bounds__(256) void k_dwconv_silu_pack(const float* __restrict__ hp,
    const float* __restrict__ wgt, const float* __restrict__ bias, float* __restrict__ xs) {
  int l = blockIdx.x*256 + threadIdx.x;
  int d = blockIdx.y; int b = blockIdx.z;
  int h0 = l >> 6, w0 = l & 63;
  const float* src = hp + ((size_t)b*DI + d)*LL;
  const float* wk = wgt + d*9;
  float acc = bias[d];
  #pragma unroll
  for (int dy=-1; dy<=1; dy++) {
    int hh = h0+dy;
    if (hh < 0 || hh >= 64) continue;
    #pragma unroll
    for (int dx=-1; dx<=1; dx++) {
      int wwp = w0+dx;
      if (wwp < 0 || wwp >= 64) continue;
      acc += wk[(dy+1)*3 + (dx+1)] * src[hh*64 + wwp];
    }
  }
  float v = acc / (1.f + __expf(-acc));   // silu
  int lt = ((l&63)<<6) | (l>>6);          // HW-transpose involution
  xs[(((size_t)b*4+0)*DI + d)*LL + l]          = v;
  xs[(((size_t)b*4+1)*DI + d)*LL + lt]         = v;
  xs[(((size_t)b*4+2)*DI + d)*LL + (LL-1-l)]   = v;
  xs[(((size_t)b*4+3)*DI + d)*LL + (LL-1-lt)]  = v;
}

// x_dbl[b,k,d,l] = sum_c x_proj_w[k,d,c] * xs[b,k,c,l]
__global__ __launch_bounds__(256) void k_proj38(const float* __restrict__ xs,
    const float* __restrict__ xpw, float* __restrict__ dbl) {
  int l = blockIdx.x*256 + threadIdx.x;
  int d = blockIdx.y; int bk = blockIdx.z; int k = bk & 3;
  const float* xc = xs + ((size_t)bk*DI)*LL + l;
  const float* wr = xpw + ((size_t)k*DBLd + d)*DI;
  float acc = 0.f;
  for (int c=0;c<DI;c++) acc += wr[c]*xc[(size_t)c*LL];
  dbl[((size_t)bk*DBLd + d)*LL + l] = acc;
}

// dts[b,k,c,l] = softplus( dt_proj_w[k,c,:] . x_dbl[b,k,0:6,l] + dt_proj_b[k,c] )
__global__ __launch_bounds__(256) void k_dt(const float* __restrict__ dbl,
    const float* __restrict__ dtw, const float* __restrict__ dtb, float* __restrict__ dts) {
  int l = blockIdx.x*256 + threadIdx.x;
  int c = blockIdx.y; int bk = blockIdx.z; int k = bk & 3;
  const float* dr = dbl + ((size_t)bk*DBLd)*LL + l;
  const float* wr = dtw + ((size_t)k*DI + c)*Rr;
  float acc = dtb[k*DI + c];
  #pragma unroll
  for (int r=0;r<Rr;r++) acc += wr[r]*dr[(size_t)r*LL];
  float dt = (acc > 20.f) ? acc : log1pf(__expf(acc));
  dts[((size_t)bk*DI + c)*LL + l] = dt;
}

// pass A: per-segment zero-init end state + decay product
__global__ __launch_bounds__(256) void k_scanA(const float* __restrict__ dts,
    const float* __restrict__ xs, const float* __restrict__ dbl,
    const float* __restrict__ A_log, float* __restrict__ hend, float* __restrict__ Pp) {
  int n = threadIdx.x & 15;
  int c = blockIdx.y*16 + (threadIdx.x >> 4);
  int seg = blockIdx.x; int bk = blockIdx.z; int k = bk & 3;
  float A = -__expf(A_log[((size_t)k*DI + c)*Ns + n]);
  const float* dtp = dts + ((size_t)bk*DI + c)*LL + seg*SEGLEN;
  const float* up  = xs  + ((size_t)bk*DI + c)*LL + seg*SEGLEN;
  const float* Bp  = dbl + ((size_t)bk*DBLd + Rr + n)*LL + seg*SEGLEN;
  float h = 0.f, sdt = 0.f;
  #pragma unroll 8
  for (int j=0;j<SEGLEN;j++) {
    float dt = dtp[j], u = up[j], Bt = Bp[j];
    h = h*__expf(dt*A) + dt*u*Bt;
    sdt += dt;
  }
  int idx = seg*NBKCN + bk*(DI*Ns) + blockIdx.y*256 + threadIdx.x;
  hend[idx] = h;
  Pp[idx] = __expf(A*sdt);
}

// sequential fix-up: segment initial states
__global__ __launch_bounds__(256) void k_scan_mid(const float* __restrict__ hend,
    const float* __restrict__ Pp, float* __restrict__ hinit) {
  int t = blockIdx.x*256 + threadIdx.x; // bkcn
  float hi = 0.f;
  for (int s=0; s<SEG; s++) {
    hinit[s*NBKCN + t] = hi;
    hi = hend[s*NBKCN + t] + Pp[s*NBKCN + t]*hi;
  }
}

// pass B: rerun segment from correct h_init, emit y
__global__ __launch_bounds__(256) void k_scanB(const float* __restrict__ dts,
    const float* __restrict__ xs, const float* __restrict__ dbl,
    const float* __restrict__ A_log, const float* __restrict__ hin, float* __restrict__ ys) {
  int n = threadIdx.x & 15;
  int c = blockIdx.y*16 + (threadIdx.x >> 4);
  int seg = blockIdx.x; int bk = blockIdx.z; int k = bk & 3;
  float A = -__expf(A_log[((size_t)k*DI + c)*Ns + n]);
  const float* dtp = dts + ((size_t)bk*DI + c)*LL + seg*SEGLEN;
  const float* up  = xs  + ((size_t)bk*DI + c)*LL + seg*SEGLEN;
  const float* Bp  = dbl + ((size_t)bk*DBLd + Rr + n)*LL + seg*SEGLEN;
  const float* Cp  = dbl + ((size_t)bk*DBLd + Rr + Ns + n)*LL + seg*SEGLEN;
  float h = hin[seg*NBKCN + bk*(DI*Ns) + blockIdx.y*256 + threadIdx.x];
  float* yp = ys + ((size_t)bk*DI + c)*LL + seg*SEGLEN;
  #pragma unroll 4
  for (int j=0;j<SEGLEN;j++) {
    float dt = dtp[j], u = up[j], Bt = Bp[j], Ct = Cp[j];
    h = h*__expf(dt*A) + dt*u*Bt;
    float p = h*Ct;
    p += __shfl_xor(p,1); p += __shfl_xor(p,2);
    p += __shfl_xor(p,4); p += __shfl_xor(p,8);
    if (n==0) yp[j] = p;
  }
}

// merge 4 directions (+ u * sum_k Ds)
__global__ __launch_bounds__(256) void k_merge(const float* __restrict__ ys,
    const float* __restrict__ xs, const float* __restrict__ Ds, float* __restrict__ yc) {
  int l = blockIdx.x*256 + threadIdx.x;
  int c = blockIdx.y; int b = blockIdx.z;
  int lt = ((l&63)<<6) | (l>>6);
  size_t s0 = (((size_t)b*4+0)*DI + c)*LL;
  size_t s1 = (((size_t)b*4+1)*DI + c)*LL;
  size_t s2 = (((size_t)b*4+2)*DI + c)*LL;
  size_t s3 = (((size_t)b*4+3)*DI + c)*LL;
  float v = ys[s0+l] + ys[s1+lt] + ys[s2+(LL-1-l)] + ys[s3+(LL-1-lt)];
  float u = xs[s0+l];
  float sd = Ds[c] + Ds[DI+c] + Ds[2*DI+c] + Ds[3*DI+c];
  yc[((size_t)b*DI + c)*LL + l] = v + u*sd;
}

// out_proj + skip, store FLOAT32 (reference output dtype is f32)
__global__ __launch_bounds__(256) void k_outproj(const float* __restrict__ y,
    const float* __restrict__ w, const float* __restrict__ x1,
    const float* __restrict__ ss, float* __restrict__ out) {
  int l = blockIdx.x*256 + threadIdx.x;
  int o0 = blockIdx.y*4; int b = blockIdx.z;
  const float* yb = y + ((size_t)b*DI)*LL + l;
  const float* w0 = w + (size_t)o0*DI;
  float a0=0.f,a1=0.f,a2=0.f,a3=0.f;
  for (int i=0;i<DI;i++) {
    float yv = yb[(size_t)i*LL];
    a0+=w0[i]*yv; a1+=w0[DI+i]*yv; a2+=w0[2*DI+i]*yv; a3+=w0[3*DI+i]*yv;
  }
  float sc = ss[0];
  const float* xb = x1 + ((size_t)b*HD + o0)*LL + l;
  size_t ob = ((size_t)b*HD + o0)*LL + l;
  out[ob]          = a0 + xb[0]*sc;
  out[ob + LL]     = a1 + xb[LL]*sc;
  out[ob + 2*LL]   = a2 + xb[2*(size_t)LL]*sc;
  out[ob + 3*LL]   = a3 + xb[3*(size_t)LL]*sc;
}

extern "C" void kernel_launch(void* const* d_in, const int* in_sizes, int n_in,
                              void* d_out, int out_size, void* d_ws, size_t ws_size,
                              hipStream_t stream) {
  const float* x         = (const float*)d_in[0];
  const float* in_conv_w = (const float*)d_in[1];
  const float* ln1_g     = (const float*)d_in[2];
  const float* ln1_b     = (const float*)d_in[3];
  const float* in_proj_w = (const float*)d_in[4];
  const float* dw_w      = (const float*)d_in[5];
  const float* dw_b      = (const float*)d_in[6];
  const float* x_proj_w  = (const float*)d_in[7];
  const float* dt_proj_w = (const float*)d_in[8];
  const float* dt_proj_b = (const float*)d_in[9];
  const float* A_log     = (const float*)d_in[10];
  const float* Ds        = (const float*)d_in[11];
  const float* onorm_g   = (const float*)d_in[12];
  const float* onorm_b   = (const float*)d_in[13];
  const float* out_proj_w= (const float*)d_in[14];
  const float* skip_s    = (const float*)d_in[15];
  float* out = (float*)d_out;

  float* ws  = (float*)d_ws;
  float* x1  = ws;                 //  786432 : post-LN (skip)
  float* hp  = x1  + 786432;       // 1572864 : in_proj out (reused as yc later)
  float* xs  = hp  + 1572864;      // 6291456 : 4-direction u
  float* dbl = xs  + 6291456;      // 1245184 : x_dbl (dt_raw | B | C)
  float* dts = dbl + 1245184;      // 6291456 : softplus dt
  float* ysb = dts + 6291456;      // 6291456 : per-direction scan out
  float* hend= ysb + 6291456;      // 1572864
  float* Pp  = hend+ 1572864;      // 1572864
  float* hin = Pp  + 1572864;      // 1572864
  float* yc  = hp;                 // reuse hp after dwconv consumed it

  dim3 blk(256);
  k_conv1x1<<<dim3(16, HD/4, Bb), blk, 0, stream>>>(x, in_conv_w, x1, HD, HD);
  k_chanln <<<dim3(Bb*LL/256), blk, 0, stream>>>(x1, ln1_g, ln1_b, HD);
  k_conv1x1<<<dim3(16, DI/4, Bb), blk, 0, stream>>>(x1, in_proj_w, hp, HD, DI);
  k_dwconv_silu_pack<<<dim3(16, DI, Bb), blk, 0, stream>>>(hp, dw_w, dw_b, xs);
  k_proj38 <<<dim3(16, DBLd, Bb*Kd), blk, 0, stream>>>(xs, x_proj_w, dbl);
  k_dt     <<<dim3(16, DI, Bb*Kd), blk, 0, stream>>>(dbl, dt_proj_w, dt_proj_b, dts);
  k_scanA  <<<dim3(SEG, DI/16, Bb*Kd), blk, 0, stream>>>(dts, xs, dbl, A_log, hend, Pp);
  k_scan_mid<<<dim3(NBKCN/256), blk, 0, stream>>>(hend, Pp, hin);
  k_scanB  <<<dim3(SEG, DI/16, Bb*Kd), blk, 0, stream>>>(dts, xs, dbl, A_log, hin, ysb);
  k_merge  <<<dim3(16, DI, Bb), blk, 0, stream>>>(ysb, xs, Ds, yc);
  k_chanln <<<dim3(Bb*LL/256), blk, 0, stream>>>(yc, onorm_g, onorm_b, DI);
  k_outproj<<<dim3(16, HD/4, Bb), blk, 0, stream>>>(yc, out_proj_w, x1, skip_s, out);
}

// Round 3
// 379.138 us; speedup vs baseline: 2.0912x; 2.0912x over previous
//
#include <hip/hip_runtime.h>
#include <hip/hip_bf16.h>

#define Bb 2
#define HD 96
#define DI 192
#define LL 4096
#define Kd 4
#define Ns 16
#define Rr 6
#define DBLd 38
#define SEG 128
#define SEGLEN 32
#define NBKCN (Bb*Kd*DI*Ns)   // 24576
#define LNEPS 1e-5f

// 1x1 conv, 8 outputs/thread: out[b,o,l] = sum_i w[o,i]*x[b,i,l]
__global__ __launch_bounds__(256) void k_conv1x1(const float* __restrict__ x,
    const float* __restrict__ w, float* __restrict__ out, int Cin, int Cout) {
  int l = blockIdx.x*256 + threadIdx.x;
  int o0 = blockIdx.y*8;
  int b = blockIdx.z;
  const float* xb = x + ((size_t)b*Cin)*LL + l;
  const float* w0 = w + (size_t)o0*Cin;
  float acc[8];
  #pragma unroll
  for (int q=0;q<8;q++) acc[q]=0.f;
  for (int i=0;i<Cin;i++) {
    float xv = xb[(size_t)i*LL];
    #pragma unroll
    for (int q=0;q<8;q++) acc[q] += w0[(size_t)q*Cin + i]*xv;
  }
  float* ob = out + ((size_t)b*Cout + o0)*LL + l;
  #pragma unroll
  for (int q=0;q<8;q++) ob[(size_t)q*LL] = acc[q];
}

// channel LayerNorm in-place over C at each (b,l)  (used for LN1 only)
__global__ __launch_bounds__(256) void k_chanln(float* __restrict__ t,
    const float* __restrict__ g, const float* __restrict__ be, int C) {
  int tt = blockIdx.x*256 + threadIdx.x;
  int l = tt & (LL-1); int b = tt >> 12;
  float* col = t + (size_t)b*C*LL + l;
  float s=0.f, s2=0.f;
  for (int i=0;i<C;i++) { float v = col[(size_t)i*LL]; s+=v; s2+=v*v; }
  float mu = s/(float)C;
  float var = s2/(float)C - mu*mu;
  float r = rsqrtf(var + LNEPS);
  for (int i=0;i<C;i++) {
    float v = col[(size_t)i*LL];
    col[(size_t)i*LL] = (v-mu)*r*g[i] + be[i];
  }
}

// depthwise 3x3 SAME + bias + silu, scatter into 4 direction copies
__global__ __launch_bounds__(256) void k_dwconv_silu_pack(const float* __restrict__ hp,
    const float* __restrict__ wgt, const float* __restrict__ bias, float* __restrict__ xs) {
  int l = blockIdx.x*256 + threadIdx.x;
  int d = blockIdx.y; int b = blockIdx.z;
  int h0 = l >> 6, w0 = l & 63;
  const float* src = hp + ((size_t)b*DI + d)*LL;
  const float* wk = wgt + d*9;
  float acc = bias[d];
  #pragma unroll
  for (int dy=-1; dy<=1; dy++) {
    int hh = h0+dy;
    if (hh < 0 || hh >= 64) continue;
    #pragma unroll
    for (int dx=-1; dx<=1; dx++) {
      int wwp = w0+dx;
      if (wwp < 0 || wwp >= 64) continue;
      acc += wk[(dy+1)*3 + (dx+1)] * src[hh*64 + wwp];
    }
  }
  float v = acc / (1.f + __expf(-acc));
  int lt = ((l&63)<<6) | (l>>6);
  xs[(((size_t)b*4+0)*DI + d)*LL + l]          = v;
  xs[(((size_t)b*4+1)*DI + d)*LL + lt]         = v;
  xs[(((size_t)b*4+2)*DI + d)*LL + (LL-1-l)]   = v;
  xs[(((size_t)b*4+3)*DI + d)*LL + (LL-1-lt)]  = v;
}

// x_dbl[b,k,d,l] = sum_c x_proj_w[k,d,c]*xs[b,k,c,l]; 19 d per block (2 groups)
__global__ __launch_bounds__(256) void k_proj38(const float* __restrict__ xs,
    const float* __restrict__ xpw, float* __restrict__ dbl) {
  int l = blockIdx.x*256 + threadIdx.x;
  int d0 = blockIdx.y*19;
  int bk = blockIdx.z; int k = bk & 3;
  const float* xc = xs + ((size_t)bk*DI)*LL + l;
  const float* wr = xpw + ((size_t)k*DBLd + d0)*DI;
  float acc[19];
  #pragma unroll
  for (int q=0;q<19;q++) acc[q]=0.f;
  for (int c=0;c<DI;c++) {
    float xv = xc[(size_t)c*LL];
    #pragma unroll
    for (int q=0;q<19;q++) acc[q] += wr[(size_t)q*DI + c]*xv;
  }
  #pragma unroll
  for (int q=0;q<19;q++) dbl[((size_t)bk*DBLd + d0 + q)*LL + l] = acc[q];
}

// dts_t[bk][l][c] = softplus(dtw.x_dbl + b), dtu_t = dt*u ; channel-last outputs
__global__ __launch_bounds__(192) void k_dtu(const float* __restrict__ xs,
    const float* __restrict__ dbl, const float* __restrict__ dtw,
    const float* __restrict__ dtb, float* __restrict__ dts_t, float* __restrict__ dtu_t) {
  int c = threadIdx.x;          // 0..191
  int l0 = blockIdx.x*16;       // 256 tiles
  int bk = blockIdx.y; int k = bk & 3;
  float w[6];
  const float* wr = dtw + ((size_t)k*DI + c)*Rr;
  #pragma unroll
  for (int r=0;r<6;r++) w[r] = wr[r];
  float bias = dtb[k*DI + c];
  const float4* up = (const float4*)(xs + ((size_t)bk*DI + c)*LL + l0);
  float4 u4[4];
  #pragma unroll
  for (int q=0;q<4;q++) u4[q] = up[q];
  const float* dr = dbl + (size_t)bk*DBLd*LL + l0;
  #pragma unroll
  for (int j=0;j<16;j++) {
    float acc = bias;
    #pragma unroll
    for (int r=0;r<6;r++) acc += w[r]*dr[(size_t)r*LL + j];
    float dt = (acc > 20.f) ? acc : log1pf(__expf(acc));
    float u = ((const float*)u4)[j];   // static after unroll
    size_t o = ((size_t)bk*LL + l0 + j)*DI + c;
    dts_t[o] = dt;
    dtu_t[o] = dt*u;
  }
}

// pass A: zero-init segment scan -> hend[seg][bk][c][n], sdt[seg][bk][c]
__global__ __launch_bounds__(192) void k_scanA(const float* __restrict__ dts_t,
    const float* __restrict__ dtu_t, const float* __restrict__ dbl,
    const float* __restrict__ A_log, float* __restrict__ hend, float* __restrict__ sdt_o) {
  int c = threadIdx.x;
  int seg = blockIdx.x; int bk = blockIdx.y; int k = bk & 3;
  float A[16];
  const float4* Ap = (const float4*)(A_log + ((size_t)k*DI + c)*Ns);
  #pragma unroll
  for (int q=0;q<4;q++) {
    float4 av = Ap[q];
    A[4*q+0]=-__expf(av.x); A[4*q+1]=-__expf(av.y);
    A[4*q+2]=-__expf(av.z); A[4*q+3]=-__expf(av.w);
  }
  int l0 = seg*SEGLEN;
  const float* dtp = dts_t + ((size_t)bk*LL + l0)*DI + c;
  const float* dup = dtu_t + ((size_t)bk*LL + l0)*DI + c;
  const float* Bp  = dbl + ((size_t)bk*DBLd + Rr)*LL + l0;
  float h[16];
  #pragma unroll
  for (int n=0;n<16;n++) h[n]=0.f;
  float sdt = 0.f;
  #pragma unroll 2
  for (int j=0;j<SEGLEN;j++) {
    float dt = dtp[(size_t)j*DI];
    float du = dup[(size_t)j*DI];
    sdt += dt;
    #pragma unroll
    for (int n=0;n<16;n++) {
      float Bn = Bp[(size_t)n*LL + j];
      h[n] = h[n]*__expf(dt*A[n]) + du*Bn;
    }
  }
  size_t base = ((size_t)seg*8 + bk)*DI*Ns + (size_t)c*Ns;
  float4* hp4 = (float4*)(hend + base);
  #pragma unroll
  for (int q=0;q<4;q++) hp4[q] = make_float4(h[4*q],h[4*q+1],h[4*q+2],h[4*q+3]);
  sdt_o[((size_t)seg*8 + bk)*DI + c] = sdt;
}

// fix-up: hend[s][t] -> h_init[s][t] in place (P recomputed from sdt)
__global__ __launch_bounds__(256) void k_fix(float* __restrict__ hend,
    const float* __restrict__ sdt, const float* __restrict__ A_log) {
  int t = blockIdx.x*256 + threadIdx.x;  // bk*3072 + c*16 + n
  int n = t & 15; int cn = t >> 4; int c = cn % DI; int bk = cn / DI; int k = bk & 3;
  float A = -__expf(A_log[((size_t)k*DI + c)*Ns + n]);
  float hi = 0.f;
  #pragma unroll 8
  for (int s=0; s<SEG; s++) {
    float he = hend[(size_t)s*NBKCN + t];
    float P  = __expf(A * sdt[(size_t)s*(8*DI) + bk*DI + c]);
    hend[(size_t)s*NBKCN + t] = hi;
    hi = he + P*hi;
  }
}

// pass B: scan from h_init, emit y into ysl (channel-last); ysl aliases dtu_t
__global__ __launch_bounds__(192) void k_scanB(const float* __restrict__ dts_t,
    float* dtu_ys, const float* __restrict__ dbl,
    const float* __restrict__ A_log, const float* __restrict__ hinit) {
  int c = threadIdx.x;
  int seg = blockIdx.x; int bk = blockIdx.y; int k = bk & 3;
  float A[16];
  const float4* Ap = (const float4*)(A_log + ((size_t)k*DI + c)*Ns);
  #pragma unroll
  for (int q=0;q<4;q++) {
    float4 av = Ap[q];
    A[4*q+0]=-__expf(av.x); A[4*q+1]=-__expf(av.y);
    A[4*q+2]=-__expf(av.z); A[4*q+3]=-__expf(av.w);
  }
  int l0 = seg*SEGLEN;
  const float* dtp = dts_t + ((size_t)bk*LL + l0)*DI + c;
  float* dup = dtu_ys + ((size_t)bk*LL + l0)*DI + c;
  const float* Bp = dbl + ((size_t)bk*DBLd + Rr)*LL + l0;
  const float* Cp = dbl + ((size_t)bk*DBLd + Rr + Ns)*LL + l0;
  float h[16];
  size_t base = ((size_t)seg*8 + bk)*DI*Ns + (size_t)c*Ns;
  const float4* hp4 = (const float4*)(hinit + base);
  #pragma unroll
  for (int q=0;q<4;q++) {
    float4 hv = hp4[q];
    h[4*q]=hv.x; h[4*q+1]=hv.y; h[4*q+2]=hv.z; h[4*q+3]=hv.w;
  }
  #pragma unroll 2
  for (int j=0;j<SEGLEN;j++) {
    float dt = dtp[(size_t)j*DI];
    float du = dup[(size_t)j*DI];
    float y = 0.f;
    #pragma unroll
    for (int n=0;n<16;n++) {
      float Bn = Bp[(size_t)n*LL + j];
      float Cn = Cp[(size_t)n*LL + j];
      h[n] = h[n]*__expf(dt*A[n]) + du*Bn;
      y += h[n]*Cn;
    }
    dup[(size_t)j*DI] = y;   // overwrite consumed dtu element
  }
}

// merge 4 directions + D-term + chanLN(192), write yn_ct[b][c][l] via LDS transpose
#define MLT 32
__global__ __launch_bounds__(192) void k_merge_ln(const float* __restrict__ ys,
    const float* __restrict__ xs, const float* __restrict__ Ds,
    const float* __restrict__ g, const float* __restrict__ be, float* __restrict__ yn_ct) {
  __shared__ float tile[DI*(MLT+1)];
  __shared__ float red[2][3];
  int c = threadIdx.x;
  int b = blockIdx.y;
  int l0 = blockIdx.x*MLT;
  float sd = Ds[c] + Ds[DI+c] + Ds[2*DI+c] + Ds[3*DI+c];
  float gg = g[c], bb = be[c];
  int wv = c >> 6, ln = c & 63;
  for (int i=0;i<MLT;i++) {
    int l = l0+i;
    int ltr = ((l&63)<<6) | (l>>6);
    float v = ys[((size_t)(b*4+0)*LL + l)*DI + c]
            + ys[((size_t)(b*4+1)*LL + ltr)*DI + c]
            + ys[((size_t)(b*4+2)*LL + (LL-1-l))*DI + c]
            + ys[((size_t)(b*4+3)*LL + (LL-1-ltr))*DI + c]
            + xs[((size_t)(b*4)*DI + c)*LL + l]*sd;
    float s = v, s2 = v*v;
    #pragma unroll
    for (int d=1; d<64; d<<=1) { s += __shfl_xor(s,d); s2 += __shfl_xor(s2,d); }
    if (ln==0) { red[0][wv]=s; red[1][wv]=s2; }
    __syncthreads();
    float S  = red[0][0]+red[0][1]+red[0][2];
    float S2 = red[1][0]+red[1][1]+red[1][2];
    __syncthreads();
    float mu = S*(1.f/DI);
    float var = S2*(1.f/DI) - mu*mu;
    float r = rsqrtf(var + LNEPS);
    tile[c*(MLT+1) + i] = (v-mu)*r*gg + bb;
  }
  __syncthreads();
  #pragma unroll 4
  for (int it=0; it<MLT; it++) {
    int idx = it*DI + c;
    int cc = idx >> 5;
    int j  = idx & 31;
    yn_ct[((size_t)b*DI + cc)*LL + l0 + j] = tile[cc*(MLT+1) + j];
  }
}

// out_proj (8 o/thread) + skip, f32 out
__global__ __launch_bounds__(256) void k_outproj(const float* __restrict__ y,
    const float* __restrict__ w, const float* __restrict__ x1,
    const float* __restrict__ ss, float* __restrict__ out) {
  int l = blockIdx.x*256 + threadIdx.x;
  int o0 = blockIdx.y*8; int b = blockIdx.z;
  const float* yb = y + ((size_t)b*DI)*LL + l;
  const float* w0 = w + (size_t)o0*DI;
  float acc[8];
  #pragma unroll
  for (int q=0;q<8;q++) acc[q]=0.f;
  for (int i=0;i<DI;i++) {
    float yv = yb[(size_t)i*LL];
    #pragma unroll
    for (int q=0;q<8;q++) acc[q] += w0[(size_t)q*DI + i]*yv;
  }
  float sc = ss[0];
  const float* xb = x1 + ((size_t)b*HD + o0)*LL + l;
  float* ob = out + ((size_t)b*HD + o0)*LL + l;
  #pragma unroll
  for (int q=0;q<8;q++) ob[(size_t)q*LL] = acc[q] + xb[(size_t)q*LL]*sc;
}

extern "C" void kernel_launch(void* const* d_in, const int* in_sizes, int n_in,
                              void* d_out, int out_size, void* d_ws, size_t ws_size,
                              hipStream_t stream) {
  const float* x         = (const float*)d_in[0];
  const float* in_conv_w = (const float*)d_in[1];
  const float* ln1_g     = (const float*)d_in[2];
  const float* ln1_b     = (const float*)d_in[3];
  const float* in_proj_w = (const float*)d_in[4];
  const float* dw_w      = (const float*)d_in[5];
  const float* dw_b      = (const float*)d_in[6];
  const float* x_proj_w  = (const float*)d_in[7];
  const float* dt_proj_w = (const float*)d_in[8];
  const float* dt_proj_b = (const float*)d_in[9];
  const float* A_log     = (const float*)d_in[10];
  const float* Ds        = (const float*)d_in[11];
  const float* onorm_g   = (const float*)d_in[12];
  const float* onorm_b   = (const float*)d_in[13];
  const float* out_proj_w= (const float*)d_in[14];
  const float* skip_s    = (const float*)d_in[15];
  float* out = (float*)d_out;

  float* ws   = (float*)d_ws;
  float* x1   = ws;                  //  786432
  float* hp   = x1   + 786432;       // 1572864  (in_proj out; later yn_ct)
  float* xs   = hp   + 1572864;      // 6291456
  float* dbl  = xs   + 6291456;      // 1245184
  float* dts_t= dbl  + 1245184;      // 6291456
  float* dtu_t= dts_t+ 6291456;      // 6291456  (later ys)
  float* hend = dtu_t+ 6291456;      // 3145728
  float* sdt  = hend + 3145728;      //  196608
  float* yn   = hp;                  // reuse

  dim3 blk(256);
  k_conv1x1<<<dim3(16, HD/8, Bb), blk, 0, stream>>>(x, in_conv_w, x1, HD, HD);
  k_chanln <<<dim3(Bb*LL/256), blk, 0, stream>>>(x1, ln1_g, ln1_b, HD);
  k_conv1x1<<<dim3(16, DI/8, Bb), blk, 0, stream>>>(x1, in_proj_w, hp, HD, DI);
  k_dwconv_silu_pack<<<dim3(16, DI, Bb), blk, 0, stream>>>(hp, dw_w, dw_b, xs);
  k_proj38 <<<dim3(16, 2, Bb*Kd), blk, 0, stream>>>(xs, x_proj_w, dbl);
  k_dtu    <<<dim3(LL/16, Bb*Kd), dim3(192), 0, stream>>>(xs, dbl, dt_proj_w, dt_proj_b, dts_t, dtu_t);
  k_scanA  <<<dim3(SEG, Bb*Kd), dim3(192), 0, stream>>>(dts_t, dtu_t, dbl, A_log, hend, sdt);
  k_fix    <<<dim3(NBKCN/256), blk, 0, stream>>>(hend, sdt, A_log);
  k_scanB  <<<dim3(SEG, Bb*Kd), dim3(192), 0, stream>>>(dts_t, dtu_t, dbl, A_log, hend);
  k_merge_ln<<<dim3(LL/MLT, Bb), dim3(192), 0, stream>>>(dtu_t, xs, Ds, onorm_g, onorm_b, yn);
  k_outproj<<<dim3(16, HD/8, Bb), blk, 0, stream>>>(yn, out_proj_w, x1, skip_s, out);
}